// Round 8
// baseline (507.069 us; speedup 1.0000x reference)
//
#include <hip/hip_runtime.h>

#define N_NODES 50000
#define N_GRAPHS 512
#define N_EDGES 800000

typedef __attribute__((ext_vector_type(8))) short short8;
typedef __attribute__((ext_vector_type(8))) unsigned short ushort8;
typedef __attribute__((ext_vector_type(8))) unsigned char uchar8;
typedef __attribute__((ext_vector_type(4))) float floatx4;

__device__ __forceinline__ float bf2f(unsigned short u) {
    union { unsigned int i; float f; } c;
    c.i = ((unsigned int)u) << 16;
    return c.f;
}
__device__ __forceinline__ unsigned short f2bf(float f) {
    union { float f; unsigned int i; } c;
    c.f = f;
    unsigned int u = c.i;
    return (unsigned short)((u + 0x7fffu + ((u >> 16) & 1u)) >> 16);
}

// ---- fp8 e4m3fn encode/decode (bit ops; subnormals flushed to 0) ----------
// encode: RNE at bit 20, clamp to ±448, flush |v|<2^-6 (error ≤0.016, far
// below the 3.6%·|v| quantization noise elsewhere).
__device__ __forceinline__ unsigned char ftofp8(float f) {
    union { float f; unsigned int u; } c; c.f = f;
    unsigned int s = (c.u >> 24) & 0x80u;
    float a = fabsf(f);
    if (a < 0x1p-6f) return (unsigned char)s;
    if (a > 448.f)   return (unsigned char)(s | 0x7E);
    unsigned int u = c.u & 0x7FFFFFFFu;
    unsigned int r = u + 0x7FFFFu + ((u >> 20) & 1u);
    return (unsigned char)(s | (((r >> 23) - 120u) << 3) | ((r >> 20) & 7u));
}
__device__ __forceinline__ float fp8tof(unsigned char uc) {
    unsigned int em = uc & 0x7Fu;
    union { unsigned int u; float f; } c;
    c.u = ((uc & 0x80u) << 24) | ((em + 960u) << 20);
    return (em < 8u) ? 0.f : c.f;
}

// async 16B global -> LDS (lane-ordered destination: ldsbase + lane*16)
__device__ __forceinline__ void g2lds16(const unsigned short* g, void* lds) {
    __builtin_amdgcn_global_load_lds(
        (const __attribute__((address_space(1))) void*)g,
        (__attribute__((address_space(3))) void*)lds, 16, 0, 0);
}

// ------ fused prep: x->fp8 + W1-3->bf16 + deg histogram + sums zeroing -----
// items: [0,1600000) x (float4 -> uchar4 fp8) | [1600000,1640960) W->bf16
//        [1640960,2440960) deg hist | [2440960,2473728) zero sums (float4)
__global__ void conv_deg(const float* __restrict__ x, const float* __restrict__ W1,
                         const float* __restrict__ W2, const float* __restrict__ W3,
                         const int* __restrict__ dst,
                         unsigned char* __restrict__ xf8, unsigned short* __restrict__ o1,
                         unsigned short* __restrict__ o2, unsigned short* __restrict__ o3,
                         int* __restrict__ deg, float4* __restrict__ sums4) {
    int i = blockIdx.x * blockDim.x + threadIdx.x;
    if (i >= 2440960) {
        int j = i - 2440960;
        if (j < 32768) sums4[j] = make_float4(0.f, 0.f, 0.f, 0.f);
        return;
    }
    if (i >= 1640960) {
        int e = i - 1640960;
        atomicAdd(&deg[dst[e]], 1);
        return;
    }
    if (i < 1600000) {
        float4 v = ((const float4*)x)[i];
        uchar4 o;
        o.x = ftofp8(v.x); o.y = ftofp8(v.y); o.z = ftofp8(v.z); o.w = ftofp8(v.w);
        ((uchar4*)xf8)[i] = o;
        return;
    }
    int j = i - 1600000;
    const float* src; unsigned short* out; int base;
    if (j < 8192)       { src = W1; out = o1; base = j; }
    else if (j < 24576) { src = W2; out = o2; base = j - 8192; }
    else                { src = W3; out = o3; base = j - 24576; }
    float4 v = ((const float4*)src)[base];
    ushort4 o;
    o.x = f2bf(v.x); o.y = f2bf(v.y); o.z = f2bf(v.z); o.w = f2bf(v.w);
    ((ushort4*)out)[base] = o;
}

// ---------------- CSR scan chain (scan2 folded into scan3) -----------------
__global__ __launch_bounds__(1024) void scan1(const int* __restrict__ deg,
                                              int* __restrict__ rowptr,
                                              int* __restrict__ blocksum) {
    __shared__ int s[1024];
    int t = threadIdx.x;
    int i = blockIdx.x * 1024 + t;
    int v = (i < N_NODES) ? deg[i] : 0;
    s[t] = v;
    __syncthreads();
    for (int off = 1; off < 1024; off <<= 1) {
        int add = (t >= off) ? s[t - off] : 0;
        __syncthreads();
        s[t] += add;
        __syncthreads();
    }
    if (i < N_NODES) rowptr[i] = s[t] - v;  // exclusive within block
    if (t == 1023) blocksum[blockIdx.x] = s[t];
}

// each block redundantly wave-scans the 49 block sums (first wave), then
// applies. Replaces the separate scan2 dispatch.
__global__ __launch_bounds__(1024) void scan3(int* __restrict__ rowptr,
                                              const int* __restrict__ blocksum,
                                              int* __restrict__ cursor) {
    __shared__ int bse[64];
    int t = threadIdx.x;
    if (t < 64) {
        const int NB = (N_NODES + 1023) / 1024;  // 49
        int orig = (t < NB) ? blocksum[t] : 0;
        int v = orig;
        for (int off = 1; off < 64; off <<= 1) {
            int u = __shfl_up(v, off, 64);
            if (t >= off) v += u;
        }
        bse[t] = v - orig;  // exclusive
    }
    __syncthreads();
    int i = blockIdx.x * 1024 + t;
    if (i < N_NODES) {
        int v = rowptr[i] + bse[i >> 10];
        rowptr[i] = v;
        cursor[i] = v;
    }
    if (i == 0) rowptr[N_NODES] = N_EDGES;
}

__global__ void scatter_csr(const int* __restrict__ src, const int* __restrict__ dst,
                            int* __restrict__ cursor, int* __restrict__ csr) {
    int e = blockIdx.x * blockDim.x + threadIdx.x;
    if (e < N_EDGES) {
        int pos = atomicAdd(&cursor[dst[e]], 1);
        csr[pos] = src[e];
    }
}

// ---- fp8 gather: rows C bytes (fp8), 8 B/lane, unroll-8; agg out bf16 -----
// Halves the per-XCD L2-miss replication traffic (the R5/R7-measured floor:
// 8 XCDs x ~43k distinct rows x rowbytes).
template <int C>
__global__ __launch_bounds__(256) void gather_f8(const unsigned char* __restrict__ h,
                                                 const int* __restrict__ rowptr,
                                                 const int* __restrict__ csr,
                                                 unsigned short* __restrict__ agg) {
    const int TPN = C / 8;       // lanes per row (uchar8 = 8 B each)
    const int NPB = 256 / TPN;
    int t = threadIdx.x;
    int n = blockIdx.x * NPB + t / TPN;
    if (n >= N_NODES) return;
    int c8 = t % TPN;
    const uchar8* hp = (const uchar8*)h + c8;
    uchar8 s = hp[(size_t)n * TPN];
    float acc[8];
#pragma unroll
    for (int j = 0; j < 8; j++) acc[j] = fp8tof(s[j]);
    int p = rowptr[n], end = rowptr[n + 1];
    for (; p + 8 <= end; p += 8) {
        int j0 = csr[p],     j1 = csr[p + 1], j2 = csr[p + 2], j3 = csr[p + 3];
        int j4 = csr[p + 4], j5 = csr[p + 5], j6 = csr[p + 6], j7 = csr[p + 7];
        uchar8 v0 = hp[(size_t)j0 * TPN];
        uchar8 v1 = hp[(size_t)j1 * TPN];
        uchar8 v2 = hp[(size_t)j2 * TPN];
        uchar8 v3 = hp[(size_t)j3 * TPN];
        uchar8 v4 = hp[(size_t)j4 * TPN];
        uchar8 v5 = hp[(size_t)j5 * TPN];
        uchar8 v6 = hp[(size_t)j6 * TPN];
        uchar8 v7 = hp[(size_t)j7 * TPN];
#pragma unroll
        for (int j = 0; j < 8; j++)
            acc[j] += ((fp8tof(v0[j]) + fp8tof(v1[j])) + (fp8tof(v2[j]) + fp8tof(v3[j]))) +
                      ((fp8tof(v4[j]) + fp8tof(v5[j])) + (fp8tof(v6[j]) + fp8tof(v7[j])));
    }
    for (; p + 4 <= end; p += 4) {
        int j0 = csr[p], j1 = csr[p + 1], j2 = csr[p + 2], j3 = csr[p + 3];
        uchar8 v0 = hp[(size_t)j0 * TPN];
        uchar8 v1 = hp[(size_t)j1 * TPN];
        uchar8 v2 = hp[(size_t)j2 * TPN];
        uchar8 v3 = hp[(size_t)j3 * TPN];
#pragma unroll
        for (int j = 0; j < 8; j++)
            acc[j] += (fp8tof(v0[j]) + fp8tof(v1[j])) + (fp8tof(v2[j]) + fp8tof(v3[j]));
    }
    for (; p < end; ++p) {
        int jj = csr[p];
        uchar8 v = hp[(size_t)jj * TPN];
#pragma unroll
        for (int j = 0; j < 8; j++) acc[j] += fp8tof(v[j]);
    }
    ushort8 o;
#pragma unroll
    for (int j = 0; j < 8; j++) o[j] = f2bf(acc[j]);
    ((ushort8*)agg)[(size_t)n * TPN + c8] = o;  // row = C bf16 = TPN*16 B
}

// ---- MFMA GEMM, BM=64/BN=128 (R6 proven), epilogue type templated ---------
// out = relu(A[M,K]bf16 @ W[256,K]^T + b); F8OUT=1 -> fp8 (single rounding
// from the fp32 accumulator), else bf16.
template <int K, int F8OUT>
__global__ __launch_bounds__(256) void gemm_mfma64(
    const unsigned short* __restrict__ A, const unsigned short* __restrict__ W,
    const float* __restrict__ bias, void* __restrict__ Cout, int M) {
    __shared__ short8 As[256];  // 4 KB: 64 A-rows x 32 k
    __shared__ short8 Ws[512];  // 8 KB: 128 W-rows x 32 k

    int tid = threadIdx.x;
    int wave = tid >> 6, lane = tid & 63;
    int wm = wave & 1, wn = wave >> 1;
    int rowbase = blockIdx.x * 64;
    int colbase = blockIdx.y * 128;
    int lkc = lane >> 4, lr = lane & 15;
    int rsw = lr ^ (lkc << 2);
    int rslot = lkc * 16 + rsw;

    int ar = rowbase + wave * 16 + rsw; if (ar >= M) ar = M - 1;
    int wr0 = colbase + (0 * 4 + wave) * 16 + rsw;
    int wr1 = colbase + (1 * 4 + wave) * 16 + rsw;
    char* asb  = (char*)As + (size_t)(wave * 64) * 16;
    char* wsb0 = (char*)Ws + (size_t)(0 * 256 + wave * 64) * 16;
    char* wsb1 = (char*)Ws + (size_t)(1 * 256 + wave * 64) * 16;

    floatx4 acc[2][4];
#pragma unroll
    for (int i = 0; i < 2; i++)
#pragma unroll
        for (int j = 0; j < 4; j++) acc[i][j] = (floatx4)(0.f);

#pragma unroll 2
    for (int k0 = 0; k0 < K; k0 += 32) {
        int ks = k0 + lkc * 8;
        g2lds16(A + (size_t)ar * K + ks, asb);
        g2lds16(W + (size_t)wr0 * K + ks, wsb0);
        g2lds16(W + (size_t)wr1 * K + ks, wsb1);
        __syncthreads();

        short8 af[2], wf[4];
#pragma unroll
        for (int mt = 0; mt < 2; mt++) af[mt] = As[(wm * 2 + mt) * 64 + rslot];
#pragma unroll
        for (int nt = 0; nt < 4; nt++) wf[nt] = Ws[(wn * 4 + nt) * 64 + rslot];
#pragma unroll
        for (int mt = 0; mt < 2; mt++)
#pragma unroll
            for (int nt = 0; nt < 4; nt++)
                acc[mt][nt] = __builtin_amdgcn_mfma_f32_16x16x32_bf16(
                    af[mt], wf[nt], acc[mt][nt], 0, 0, 0);
        __syncthreads();
    }

    // C/D layout: col=lane&15, row=(lane>>4)*4+reg
#pragma unroll
    for (int mt = 0; mt < 2; mt++) {
#pragma unroll
        for (int reg = 0; reg < 4; reg++) {
            int row = rowbase + (wm * 2 + mt) * 16 + lkc * 4 + reg;
            if (row >= M) continue;
#pragma unroll
            for (int nt = 0; nt < 4; nt++) {
                int col = colbase + (wn * 4 + nt) * 16 + lr;
                float v = fmaxf(acc[mt][nt][reg] + bias[col], 0.f);
                if (F8OUT)
                    ((unsigned char*)Cout)[(size_t)row * 256 + col] = ftofp8(v);
                else
                    ((unsigned short*)Cout)[(size_t)row * 256 + col] = f2bf(v);
            }
        }
    }
}

// ------- mean pool, stage 1: streaming accumulate into fp32 sums -----------
__global__ __launch_bounds__(256) void pool_accum(const unsigned short* __restrict__ h,
                                                  const int* __restrict__ batch,
                                                  float* __restrict__ sums) {
    int t = threadIdx.x;  // column 0..255
    int r0 = blockIdx.x * 32;
    int r1 = r0 + 32; if (r1 > N_NODES) r1 = N_NODES;
    if (r0 >= N_NODES) return;
    float acc = 0.f;
    int gcur = batch[r0];
    for (int r = r0; r < r1; ++r) {
        int g = batch[r];
        if (g != gcur) { atomicAdd(&sums[gcur * 256 + t], acc); acc = 0.f; gcur = g; }
        acc += bf2f(h[(size_t)r * 256 + t]);
    }
    atomicAdd(&sums[gcur * 256 + t], acc);
}

// ------- mean pool, stage 2: divide + MLP head (one block per graph) -------
__global__ __launch_bounds__(128) void head(const float* __restrict__ sums,
                                            const int* __restrict__ batch,
                                            const float* __restrict__ Wf1,
                                            const float* __restrict__ bf1,
                                            const float* __restrict__ Wf2,
                                            const float* __restrict__ bf2,
                                            float* __restrict__ out) {
    __shared__ float hg[256];
    __shared__ float hid[128];
    int g = blockIdx.x;
    int t = threadIdx.x;
    int lo = 0, hi = N_NODES;
    while (lo < hi) { int m = (lo + hi) >> 1; if (batch[m] < g) lo = m + 1; else hi = m; }
    int start = lo;
    lo = 0; hi = N_NODES;
    while (lo < hi) { int m = (lo + hi) >> 1; if (batch[m] < g + 1) lo = m + 1; else hi = m; }
    int end = lo;
    float inv = 1.0f / fmaxf((float)(end - start), 1.0f);
    hg[t]       = sums[g * 256 + t] * inv;
    hg[t + 128] = sums[g * 256 + t + 128] * inv;
    __syncthreads();
    float a1 = bf1[t];
    for (int c = 0; c < 256; c++) a1 += hg[c] * Wf1[t * 256 + c];
    hid[t] = fmaxf(a1, 0.f);
    __syncthreads();
    if (t < 10) {
        float a = bf2[t];
        for (int j = 0; j < 128; j++) a += hid[j] * Wf2[t * 128 + j];
        out[g * 10 + t] = a;
    }
}

extern "C" void kernel_launch(void* const* d_in, const int* in_sizes, int n_in,
                              void* d_out, int out_size, void* d_ws, size_t ws_size,
                              hipStream_t stream) {
    const float* x   = (const float*)d_in[0];
    const int*  edge = (const int*)d_in[1];
    const int*  batch= (const int*)d_in[2];
    const float* W1  = (const float*)d_in[3];
    const float* b1  = (const float*)d_in[4];
    const float* W2  = (const float*)d_in[5];
    const float* b2  = (const float*)d_in[6];
    const float* W3  = (const float*)d_in[7];
    const float* b3  = (const float*)d_in[8];
    const float* Wf1 = (const float*)d_in[9];
    const float* bf1 = (const float*)d_in[10];
    const float* Wf2 = (const float*)d_in[11];
    const float* bf2 = (const float*)d_in[12];
    const int* src = edge;
    const int* dst = edge + N_EDGES;

    char* wsb = (char*)d_ws;
    size_t off = 0;
    auto alloc = [&](size_t bytes) { void* p = wsb + off; off += (bytes + 255) & ~(size_t)255; return p; };
    unsigned char*  x_f8  = (unsigned char*)alloc((size_t)N_NODES * 128);
    unsigned char*  h1_f8 = (unsigned char*)alloc((size_t)N_NODES * 256);
    unsigned char*  h2_f8 = (unsigned char*)alloc((size_t)N_NODES * 256);
    unsigned short* agg_bf= (unsigned short*)alloc((size_t)N_NODES * 256 * 2);
    unsigned short* hA_bf = (unsigned short*)alloc((size_t)N_NODES * 256 * 2);
    unsigned short* W1bf  = (unsigned short*)alloc(256 * 128 * 2);
    unsigned short* W2bf  = (unsigned short*)alloc(256 * 256 * 2);
    unsigned short* W3bf  = (unsigned short*)alloc(256 * 256 * 2);
    int* rowptr   = (int*)alloc((N_NODES + 4) * 4);
    int* cursor   = (int*)alloc(N_NODES * 4);
    int* deg      = (int*)alloc(N_NODES * 4);
    int* csr      = (int*)alloc(N_EDGES * 4);
    int* blocksum = (int*)alloc(64 * 4);
    float* sums   = (float*)alloc((size_t)N_GRAPHS * 256 * 4);

    const int NB_SCAN = (N_NODES + 1023) / 1024;  // 49

    // ---- prep: memset deg; conv(x->fp8, W->bf16)+hist+zero in one kernel --
    hipMemsetAsync(deg, 0, N_NODES * sizeof(int), stream);
    conv_deg<<<(2473728 + 255) / 256, 256, 0, stream>>>(
        x, W1, W2, W3, dst, x_f8, W1bf, W2bf, W3bf, deg, (float4*)sums);

    // ---- CSR: scan1 + (scan2 folded into scan3) + scatter ----
    scan1<<<NB_SCAN, 1024, 0, stream>>>(deg, rowptr, blocksum);
    scan3<<<NB_SCAN, 1024, 0, stream>>>(rowptr, blocksum, cursor);
    scatter_csr<<<(N_EDGES + 255) / 256, 256, 0, stream>>>(src, dst, cursor, csr);

    dim3 ggrid((N_NODES + 63) / 64, 2);  // 782 x 2 = 1564 blocks

    // ---- layer 1 (K=128): fp8 gather -> bf16 agg -> GEMM -> fp8 h1 ----
    gather_f8<128><<<(N_NODES + 15) / 16, 256, 0, stream>>>(x_f8, rowptr, csr, agg_bf);
    gemm_mfma64<128, 1><<<ggrid, 256, 0, stream>>>(agg_bf, W1bf, b1, h1_f8, N_NODES);

    // ---- layer 2 (K=256) ----
    gather_f8<256><<<(N_NODES + 7) / 8, 256, 0, stream>>>(h1_f8, rowptr, csr, agg_bf);
    gemm_mfma64<256, 1><<<ggrid, 256, 0, stream>>>(agg_bf, W2bf, b2, h2_f8, N_NODES);

    // ---- layer 3 (K=256): bf16 output for the pool ----
    gather_f8<256><<<(N_NODES + 7) / 8, 256, 0, stream>>>(h2_f8, rowptr, csr, agg_bf);
    gemm_mfma64<256, 0><<<ggrid, 256, 0, stream>>>(agg_bf, W3bf, b3, hA_bf, N_NODES);

    // ---- mean pool (sums pre-zeroed in conv_deg) + head ----
    pool_accum<<<(N_NODES + 31) / 32, 256, 0, stream>>>(hA_bf, batch, sums);
    head<<<N_GRAPHS, 128, 0, stream>>>(sums, batch, Wf1, bf1, Wf2, bf2, (float*)d_out);
}

// Round 9
// 380.377 us; speedup vs baseline: 1.3331x; 1.3331x over previous
//
#include <hip/hip_runtime.h>

#define N_NODES 50000
#define N_GRAPHS 512
#define N_EDGES 800000

typedef __attribute__((ext_vector_type(8))) short short8;
typedef __attribute__((ext_vector_type(8))) unsigned short ushort8;
typedef __attribute__((ext_vector_type(4))) float floatx4;
typedef __attribute__((ext_vector_type(2))) float floatx2;

__device__ __forceinline__ float bf2f(unsigned short u) {
    union { unsigned int i; float f; } c;
    c.i = ((unsigned int)u) << 16;
    return c.f;
}
__device__ __forceinline__ unsigned short f2bf(float f) {
    union { float f; unsigned int i; } c;
    c.f = f;
    unsigned int u = c.i;
    return (unsigned short)((u + 0x7fffu + ((u >> 16) & 1u)) >> 16);
}

// ---- fp8 e4m3fn encode (software RNE, clamp ±448, flush |v|<2^-6) ---------
// decode is done by HW v_cvt_pk_f32_fp8 (exact widening, OCP on gfx950).
__device__ __forceinline__ unsigned char ftofp8(float f) {
    union { float f; unsigned int u; } c; c.f = f;
    unsigned int s = (c.u >> 24) & 0x80u;
    float a = fabsf(f);
    if (a < 0x1p-6f) return (unsigned char)s;
    if (a > 448.f)   return (unsigned char)(s | 0x7E);
    unsigned int u = c.u & 0x7FFFFFFFu;
    unsigned int r = u + 0x7FFFFu + ((u >> 20) & 1u);
    return (unsigned char)(s | (((r >> 23) - 120u) << 3) | ((r >> 20) & 7u));
}

// HW decode of 8 packed fp8 (uint2) accumulated into acc[8]
__device__ __forceinline__ void f8acc(float* acc, uint2 v) {
    floatx2 a = __builtin_amdgcn_cvt_pk_f32_fp8(v.x, false);
    floatx2 b = __builtin_amdgcn_cvt_pk_f32_fp8(v.x, true);
    floatx2 c = __builtin_amdgcn_cvt_pk_f32_fp8(v.y, false);
    floatx2 d = __builtin_amdgcn_cvt_pk_f32_fp8(v.y, true);
    acc[0] += a[0]; acc[1] += a[1]; acc[2] += b[0]; acc[3] += b[1];
    acc[4] += c[0]; acc[5] += c[1]; acc[6] += d[0]; acc[7] += d[1];
}

// async 16B global -> LDS (lane-ordered destination: ldsbase + lane*16)
__device__ __forceinline__ void g2lds16(const unsigned short* g, void* lds) {
    __builtin_amdgcn_global_load_lds(
        (const __attribute__((address_space(1))) void*)g,
        (__attribute__((address_space(3))) void*)lds, 16, 0, 0);
}

// ------ fused prep: x->fp8 + W1-3->bf16 + deg histogram + sums zeroing -----
// items: [0,1600000) x (float4 -> uchar4 fp8) | [1600000,1640960) W->bf16
//        [1640960,2440960) deg hist | [2440960,2473728) zero sums (float4)
__global__ void conv_deg(const float* __restrict__ x, const float* __restrict__ W1,
                         const float* __restrict__ W2, const float* __restrict__ W3,
                         const int* __restrict__ dst,
                         unsigned char* __restrict__ xf8, unsigned short* __restrict__ o1,
                         unsigned short* __restrict__ o2, unsigned short* __restrict__ o3,
                         int* __restrict__ deg, float4* __restrict__ sums4) {
    int i = blockIdx.x * blockDim.x + threadIdx.x;
    if (i >= 2440960) {
        int j = i - 2440960;
        if (j < 32768) sums4[j] = make_float4(0.f, 0.f, 0.f, 0.f);
        return;
    }
    if (i >= 1640960) {
        int e = i - 1640960;
        atomicAdd(&deg[dst[e]], 1);
        return;
    }
    if (i < 1600000) {
        float4 v = ((const float4*)x)[i];
        uchar4 o;
        o.x = ftofp8(v.x); o.y = ftofp8(v.y); o.z = ftofp8(v.z); o.w = ftofp8(v.w);
        ((uchar4*)xf8)[i] = o;
        return;
    }
    int j = i - 1600000;
    const float* src; unsigned short* out; int base;
    if (j < 8192)       { src = W1; out = o1; base = j; }
    else if (j < 24576) { src = W2; out = o2; base = j - 8192; }
    else                { src = W3; out = o3; base = j - 24576; }
    float4 v = ((const float4*)src)[base];
    ushort4 o;
    o.x = f2bf(v.x); o.y = f2bf(v.y); o.z = f2bf(v.z); o.w = f2bf(v.w);
    ((ushort4*)out)[base] = o;
}

// ---------------- CSR scan chain (scan2 folded into scan3) -----------------
__global__ __launch_bounds__(1024) void scan1(const int* __restrict__ deg,
                                              int* __restrict__ rowptr,
                                              int* __restrict__ blocksum) {
    __shared__ int s[1024];
    int t = threadIdx.x;
    int i = blockIdx.x * 1024 + t;
    int v = (i < N_NODES) ? deg[i] : 0;
    s[t] = v;
    __syncthreads();
    for (int off = 1; off < 1024; off <<= 1) {
        int add = (t >= off) ? s[t - off] : 0;
        __syncthreads();
        s[t] += add;
        __syncthreads();
    }
    if (i < N_NODES) rowptr[i] = s[t] - v;  // exclusive within block
    if (t == 1023) blocksum[blockIdx.x] = s[t];
}

// each block redundantly wave-scans the 49 block sums (first wave), then
// applies. Replaces the separate scan2 dispatch.
__global__ __launch_bounds__(1024) void scan3(int* __restrict__ rowptr,
                                              const int* __restrict__ blocksum,
                                              int* __restrict__ cursor) {
    __shared__ int bse[64];
    int t = threadIdx.x;
    if (t < 64) {
        const int NB = (N_NODES + 1023) / 1024;  // 49
        int orig = (t < NB) ? blocksum[t] : 0;
        int v = orig;
        for (int off = 1; off < 64; off <<= 1) {
            int u = __shfl_up(v, off, 64);
            if (t >= off) v += u;
        }
        bse[t] = v - orig;  // exclusive
    }
    __syncthreads();
    int i = blockIdx.x * 1024 + t;
    if (i < N_NODES) {
        int v = rowptr[i] + bse[i >> 10];
        rowptr[i] = v;
        cursor[i] = v;
    }
    if (i == 0) rowptr[N_NODES] = N_EDGES;
}

__global__ void scatter_csr(const int* __restrict__ src, const int* __restrict__ dst,
                            int* __restrict__ cursor, int* __restrict__ csr) {
    int e = blockIdx.x * blockDim.x + threadIdx.x;
    if (e < N_EDGES) {
        int pos = atomicAdd(&cursor[dst[e]], 1);
        csr[pos] = src[e];
    }
}

// ---- fp8 gather: rows C bytes, 8 B/lane, unroll-8, HW cvt decode ----------
// R8 proved the byte-halving (FETCH 185->81 MB) but software decode was
// 72% VALU. v_cvt_pk_f32_fp8 decodes 2 elems/inst -> fetch-path-bound again.
template <int C>
__global__ __launch_bounds__(256) void gather_f8(const unsigned char* __restrict__ h,
                                                 const int* __restrict__ rowptr,
                                                 const int* __restrict__ csr,
                                                 unsigned short* __restrict__ agg) {
    const int TPN = C / 8;       // lanes per row (8 B each)
    const int NPB = 256 / TPN;
    int t = threadIdx.x;
    int n = blockIdx.x * NPB + t / TPN;
    if (n >= N_NODES) return;
    int c8 = t % TPN;
    const uint2* hp = (const uint2*)h + c8;
    float acc[8];
#pragma unroll
    for (int j = 0; j < 8; j++) acc[j] = 0.f;
    f8acc(acc, hp[(size_t)n * TPN]);  // self row
    int p = rowptr[n], end = rowptr[n + 1];
    for (; p + 8 <= end; p += 8) {
        int j0 = csr[p],     j1 = csr[p + 1], j2 = csr[p + 2], j3 = csr[p + 3];
        int j4 = csr[p + 4], j5 = csr[p + 5], j6 = csr[p + 6], j7 = csr[p + 7];
        uint2 v0 = hp[(size_t)j0 * TPN];
        uint2 v1 = hp[(size_t)j1 * TPN];
        uint2 v2 = hp[(size_t)j2 * TPN];
        uint2 v3 = hp[(size_t)j3 * TPN];
        uint2 v4 = hp[(size_t)j4 * TPN];
        uint2 v5 = hp[(size_t)j5 * TPN];
        uint2 v6 = hp[(size_t)j6 * TPN];
        uint2 v7 = hp[(size_t)j7 * TPN];
        f8acc(acc, v0); f8acc(acc, v1); f8acc(acc, v2); f8acc(acc, v3);
        f8acc(acc, v4); f8acc(acc, v5); f8acc(acc, v6); f8acc(acc, v7);
    }
    for (; p + 4 <= end; p += 4) {
        int j0 = csr[p], j1 = csr[p + 1], j2 = csr[p + 2], j3 = csr[p + 3];
        uint2 v0 = hp[(size_t)j0 * TPN];
        uint2 v1 = hp[(size_t)j1 * TPN];
        uint2 v2 = hp[(size_t)j2 * TPN];
        uint2 v3 = hp[(size_t)j3 * TPN];
        f8acc(acc, v0); f8acc(acc, v1); f8acc(acc, v2); f8acc(acc, v3);
    }
    for (; p < end; ++p) {
        uint2 v = hp[(size_t)csr[p] * TPN];
        f8acc(acc, v);
    }
    ushort8 o;
#pragma unroll
    for (int j = 0; j < 8; j++) o[j] = f2bf(acc[j]);
    ((ushort8*)agg)[(size_t)n * TPN + c8] = o;  // row = C bf16 = TPN*16 B
}

// ---- MFMA GEMM, BM=64/BN=128 (R6 proven), epilogue type templated ---------
// out = relu(A[M,K]bf16 @ W[256,K]^T + b); F8OUT=1 -> fp8 (single rounding
// from the fp32 accumulator), else bf16.
template <int K, int F8OUT>
__global__ __launch_bounds__(256) void gemm_mfma64(
    const unsigned short* __restrict__ A, const unsigned short* __restrict__ W,
    const float* __restrict__ bias, void* __restrict__ Cout, int M) {
    __shared__ short8 As[256];  // 4 KB: 64 A-rows x 32 k
    __shared__ short8 Ws[512];  // 8 KB: 128 W-rows x 32 k

    int tid = threadIdx.x;
    int wave = tid >> 6, lane = tid & 63;
    int wm = wave & 1, wn = wave >> 1;
    int rowbase = blockIdx.x * 64;
    int colbase = blockIdx.y * 128;
    int lkc = lane >> 4, lr = lane & 15;
    int rsw = lr ^ (lkc << 2);
    int rslot = lkc * 16 + rsw;

    int ar = rowbase + wave * 16 + rsw; if (ar >= M) ar = M - 1;
    int wr0 = colbase + (0 * 4 + wave) * 16 + rsw;
    int wr1 = colbase + (1 * 4 + wave) * 16 + rsw;
    char* asb  = (char*)As + (size_t)(wave * 64) * 16;
    char* wsb0 = (char*)Ws + (size_t)(0 * 256 + wave * 64) * 16;
    char* wsb1 = (char*)Ws + (size_t)(1 * 256 + wave * 64) * 16;

    floatx4 acc[2][4];
#pragma unroll
    for (int i = 0; i < 2; i++)
#pragma unroll
        for (int j = 0; j < 4; j++) acc[i][j] = (floatx4)(0.f);

#pragma unroll 2
    for (int k0 = 0; k0 < K; k0 += 32) {
        int ks = k0 + lkc * 8;
        g2lds16(A + (size_t)ar * K + ks, asb);
        g2lds16(W + (size_t)wr0 * K + ks, wsb0);
        g2lds16(W + (size_t)wr1 * K + ks, wsb1);
        __syncthreads();

        short8 af[2], wf[4];
#pragma unroll
        for (int mt = 0; mt < 2; mt++) af[mt] = As[(wm * 2 + mt) * 64 + rslot];
#pragma unroll
        for (int nt = 0; nt < 4; nt++) wf[nt] = Ws[(wn * 4 + nt) * 64 + rslot];
#pragma unroll
        for (int mt = 0; mt < 2; mt++)
#pragma unroll
            for (int nt = 0; nt < 4; nt++)
                acc[mt][nt] = __builtin_amdgcn_mfma_f32_16x16x32_bf16(
                    af[mt], wf[nt], acc[mt][nt], 0, 0, 0);
        __syncthreads();
    }

    // C/D layout: col=lane&15, row=(lane>>4)*4+reg
#pragma unroll
    for (int mt = 0; mt < 2; mt++) {
#pragma unroll
        for (int reg = 0; reg < 4; reg++) {
            int row = rowbase + (wm * 2 + mt) * 16 + lkc * 4 + reg;
            if (row >= M) continue;
#pragma unroll
            for (int nt = 0; nt < 4; nt++) {
                int col = colbase + (wn * 4 + nt) * 16 + lr;
                float v = fmaxf(acc[mt][nt][reg] + bias[col], 0.f);
                if (F8OUT)
                    ((unsigned char*)Cout)[(size_t)row * 256 + col] = ftofp8(v);
                else
                    ((unsigned short*)Cout)[(size_t)row * 256 + col] = f2bf(v);
            }
        }
    }
}

// ------- mean pool, stage 1: streaming accumulate into fp32 sums -----------
__global__ __launch_bounds__(256) void pool_accum(const unsigned short* __restrict__ h,
                                                  const int* __restrict__ batch,
                                                  float* __restrict__ sums) {
    int t = threadIdx.x;  // column 0..255
    int r0 = blockIdx.x * 32;
    int r1 = r0 + 32; if (r1 > N_NODES) r1 = N_NODES;
    if (r0 >= N_NODES) return;
    float acc = 0.f;
    int gcur = batch[r0];
    for (int r = r0; r < r1; ++r) {
        int g = batch[r];
        if (g != gcur) { atomicAdd(&sums[gcur * 256 + t], acc); acc = 0.f; gcur = g; }
        acc += bf2f(h[(size_t)r * 256 + t]);
    }
    atomicAdd(&sums[gcur * 256 + t], acc);
}

// ------- mean pool, stage 2: divide + MLP head (one block per graph) -------
__global__ __launch_bounds__(128) void head(const float* __restrict__ sums,
                                            const int* __restrict__ batch,
                                            const float* __restrict__ Wf1,
                                            const float* __restrict__ bf1,
                                            const float* __restrict__ Wf2,
                                            const float* __restrict__ bf2,
                                            float* __restrict__ out) {
    __shared__ float hg[256];
    __shared__ float hid[128];
    int g = blockIdx.x;
    int t = threadIdx.x;
    int lo = 0, hi = N_NODES;
    while (lo < hi) { int m = (lo + hi) >> 1; if (batch[m] < g) lo = m + 1; else hi = m; }
    int start = lo;
    lo = 0; hi = N_NODES;
    while (lo < hi) { int m = (lo + hi) >> 1; if (batch[m] < g + 1) lo = m + 1; else hi = m; }
    int end = lo;
    float inv = 1.0f / fmaxf((float)(end - start), 1.0f);
    hg[t]       = sums[g * 256 + t] * inv;
    hg[t + 128] = sums[g * 256 + t + 128] * inv;
    __syncthreads();
    float a1 = bf1[t];
    for (int c = 0; c < 256; c++) a1 += hg[c] * Wf1[t * 256 + c];
    hid[t] = fmaxf(a1, 0.f);
    __syncthreads();
    if (t < 10) {
        float a = bf2[t];
        for (int j = 0; j < 128; j++) a += hid[j] * Wf2[t * 128 + j];
        out[g * 10 + t] = a;
    }
}

extern "C" void kernel_launch(void* const* d_in, const int* in_sizes, int n_in,
                              void* d_out, int out_size, void* d_ws, size_t ws_size,
                              hipStream_t stream) {
    const float* x   = (const float*)d_in[0];
    const int*  edge = (const int*)d_in[1];
    const int*  batch= (const int*)d_in[2];
    const float* W1  = (const float*)d_in[3];
    const float* b1  = (const float*)d_in[4];
    const float* W2  = (const float*)d_in[5];
    const float* b2  = (const float*)d_in[6];
    const float* W3  = (const float*)d_in[7];
    const float* b3  = (const float*)d_in[8];
    const float* Wf1 = (const float*)d_in[9];
    const float* bf1 = (const float*)d_in[10];
    const float* Wf2 = (const float*)d_in[11];
    const float* bf2 = (const float*)d_in[12];
    const int* src = edge;
    const int* dst = edge + N_EDGES;

    char* wsb = (char*)d_ws;
    size_t off = 0;
    auto alloc = [&](size_t bytes) { void* p = wsb + off; off += (bytes + 255) & ~(size_t)255; return p; };
    unsigned char*  x_f8  = (unsigned char*)alloc((size_t)N_NODES * 128);
    unsigned char*  h1_f8 = (unsigned char*)alloc((size_t)N_NODES * 256);
    unsigned char*  h2_f8 = (unsigned char*)alloc((size_t)N_NODES * 256);
    unsigned short* agg_bf= (unsigned short*)alloc((size_t)N_NODES * 256 * 2);
    unsigned short* hA_bf = (unsigned short*)alloc((size_t)N_NODES * 256 * 2);
    unsigned short* W1bf  = (unsigned short*)alloc(256 * 128 * 2);
    unsigned short* W2bf  = (unsigned short*)alloc(256 * 256 * 2);
    unsigned short* W3bf  = (unsigned short*)alloc(256 * 256 * 2);
    int* rowptr   = (int*)alloc((N_NODES + 4) * 4);
    int* cursor   = (int*)alloc(N_NODES * 4);
    int* deg      = (int*)alloc(N_NODES * 4);
    int* csr      = (int*)alloc(N_EDGES * 4);
    int* blocksum = (int*)alloc(64 * 4);
    float* sums   = (float*)alloc((size_t)N_GRAPHS * 256 * 4);

    const int NB_SCAN = (N_NODES + 1023) / 1024;  // 49

    // ---- prep: memset deg; conv(x->fp8, W->bf16)+hist+zero in one kernel --
    hipMemsetAsync(deg, 0, N_NODES * sizeof(int), stream);
    conv_deg<<<(2473728 + 255) / 256, 256, 0, stream>>>(
        x, W1, W2, W3, dst, x_f8, W1bf, W2bf, W3bf, deg, (float4*)sums);

    // ---- CSR: scan1 + (scan2 folded into scan3) + scatter ----
    scan1<<<NB_SCAN, 1024, 0, stream>>>(deg, rowptr, blocksum);
    scan3<<<NB_SCAN, 1024, 0, stream>>>(rowptr, blocksum, cursor);
    scatter_csr<<<(N_EDGES + 255) / 256, 256, 0, stream>>>(src, dst, cursor, csr);

    dim3 ggrid((N_NODES + 63) / 64, 2);  // 782 x 2 = 1564 blocks

    // ---- layer 1 (K=128): fp8 gather -> bf16 agg -> GEMM -> fp8 h1 ----
    gather_f8<128><<<(N_NODES + 15) / 16, 256, 0, stream>>>(x_f8, rowptr, csr, agg_bf);
    gemm_mfma64<128, 1><<<ggrid, 256, 0, stream>>>(agg_bf, W1bf, b1, h1_f8, N_NODES);

    // ---- layer 2 (K=256) ----
    gather_f8<256><<<(N_NODES + 7) / 8, 256, 0, stream>>>(h1_f8, rowptr, csr, agg_bf);
    gemm_mfma64<256, 1><<<ggrid, 256, 0, stream>>>(agg_bf, W2bf, b2, h2_f8, N_NODES);

    // ---- layer 3 (K=256): bf16 output for the pool ----
    gather_f8<256><<<(N_NODES + 7) / 8, 256, 0, stream>>>(h2_f8, rowptr, csr, agg_bf);
    gemm_mfma64<256, 0><<<ggrid, 256, 0, stream>>>(agg_bf, W3bf, b3, hA_bf, N_NODES);

    // ---- mean pool (sums pre-zeroed in conv_deg) + head ----
    pool_accum<<<(N_NODES + 31) / 32, 256, 0, stream>>>(hA_bf, batch, sums);
    head<<<N_GRAPHS, 128, 0, stream>>>(sums, batch, Wf1, bf1, Wf2, bf2, (float*)d_out);
}